// Round 15
// baseline (92.792 us; speedup 1.0000x reference)
//
#include <hip/hip_runtime.h>

// ---------- types ----------
typedef __attribute__((ext_vector_type(8))) short short8;     // 8 bf16 (4 VGPRs)
typedef __attribute__((ext_vector_type(4))) float floatx4;    // MFMA C/D & NT loads
typedef __attribute__((ext_vector_type(4))) unsigned int uintx4;

// ---------- fp32 -> packed bf16x2 (RNE) ----------
#if __has_builtin(__builtin_amdgcn_cvt_pk_bf16_f32)
typedef __attribute__((ext_vector_type(2))) __bf16 bf16x2;
__device__ __forceinline__ unsigned int pk_bf16(float a, float b) {
  bf16x2 v = __builtin_amdgcn_cvt_pk_bf16_f32(a, b);
  return __builtin_bit_cast(unsigned int, v);
}
#else
__device__ __forceinline__ unsigned int bf16_1(float f) {
  unsigned int u = __builtin_bit_cast(unsigned int, f);
  return (u + 0x7fffu + ((u >> 16) & 1u)) >> 16;
}
__device__ __forceinline__ unsigned int pk_bf16(float a, float b) {
  return bf16_1(a) | (bf16_1(b) << 16);
}
#endif

// Fragment conventions (verified rounds 0-14, absmax 3.9e-3):
//   A-frag (16x16x32): lane(ln,quad) holds A[m=ln][k=quad*8+j], j=0..7
//   B-frag:            lane(ln,quad) holds B[n=ln][k=quad*8+j]  (B[k][n]=W[c][r][k], n=r*8+c)
//   C/D:               col=ln, row=quad*4+reg
// Bprep frag id: Fb = ((mod*8 + h)*24 + ks)*4 + nt, n16 = h*4+nt; frag = 64 lanes x 16B.
//
// LEDGER OF DEAD ENDS (do not revisit without new evidence):
// * STORE GEOMETRY LOAD-BEARING: scalar dword stores, 16 consecutive dwords
//   per 16-lane group x 4 rows/instr = 1.0x writes. Anything else 1.5-3.0x.
// * NT STORES: 3x write amplification (r3). NT-loads-alone was never
//   isolated until THIS round (r3 bundled it with the store bug).
// * PERMUTED-B + direct stores: silent transpose (round 6).
// * REG-SPILL SIGNATURE: WRITE 612 MB / FETCH 211 MB / 2.4x dur (round 7).
// * 64-ROW 16-WAVE BLOCKS: quantization tax (round 9).
// * OCCUPANCY 43->76%: zero effect (round 10).
// * PREFETCH DEPTH 2->3: zero effect (round 11).
// * 64x256 COL-SPLIT: X HBM doubles, L3 does not absorb (round 12).
// * PER-WAVE K-STAGGER: zero effect (round 13).
// * VALU DIET (full unroll, imm stores): VALUBusy 29->19, zero effect (r14).
// ROUND-15 THEORY: X STREAMING EVICTS B FROM L2 -> B is served by L3 at
// ~15 TB/s (saturated) -> explains ALL nulls (BW-saturation is invariant
// to waves/depth/stagger/VALU). Test: NT on the 12 staging X loads ONLY.
// Signature: FETCH jumps to ~150 MB. If dur drops to 60-72, confirmed;
// if dur rises ~+10 (pure HBM cost), theory dead -> structure floor.

// ============================================================
// Prepass W: [8][64][768] fp32 -> bf16 B-fragments; bias permuted to n-order.
// ============================================================
__global__ __launch_bounds__(256) void prep_w(
    const float* __restrict__ Wi, const float* __restrict__ Wc, const float* __restrict__ Wd,
    const float* __restrict__ bi, const float* __restrict__ bc, const float* __restrict__ bd,
    uintx4* __restrict__ Bprep, float* __restrict__ biasPrep) {
  const int t = blockIdx.x * 256 + threadIdx.x;  // 0 .. 147455
  const int l = t & 63;
  const int frag = t >> 6;             // 0 .. 2303
  const int nt = frag & 3;
  const int q = frag >> 2;
  const int ks = q % 24;
  const int q2 = q / 24;
  const int h = q2 & 7;
  const int mod = q2 >> 3;
  const int n16 = h * 4 + nt;
  const float* __restrict__ W = (mod == 0) ? Wi : ((mod == 1) ? Wc : Wd);

  const int n = n16 * 16 + (l & 15);
  const int r = n >> 3;
  const int c = n & 7;
  const int i0 = ks * 32 + (l >> 4) * 8;
  const float* src = W + (size_t)(c * 64 + r) * 768 + i0;
  floatx4 f0 = *(const floatx4*)(src);
  floatx4 f1 = *(const floatx4*)(src + 4);
  uintx4 p;
  p.x = pk_bf16(f0.x, f0.y);
  p.y = pk_bf16(f0.z, f0.w);
  p.z = pk_bf16(f1.x, f1.y);
  p.w = pk_bf16(f1.z, f1.w);
  Bprep[(size_t)frag * 64 + l] = p;

  if (t < 1536) {
    const int m2 = t >> 9;
    const int nn = t & 511;
    const float* bb = (m2 == 0) ? bi : ((m2 == 1) ? bc : bd);
    biasPrep[t] = bb[(nn & 7) * 64 + (nn >> 3)];
  }
}

// ============================================================
// Fused GEMM + squash. ROUND-15 = round-14 kernel with ONE change:
// the 12 staging X loads are NONTEMPORAL (keep the X stream out of L2
// so the per-XCD 768 KB Bprep slice stays L2-resident).
//   Block: 512 thr / 8 waves; wave owns 32x64 (acc[2][4] = 32 AGPR).
//   A (32x768) staged once as bf16 frags in 48 KB LDS (slot-XOR), one
//   barrier, fully-unrolled 24-step K-loop, 3-deep register prefetch.
//   Epilogue: shuffle-squash + rsq/rcp + imm-offset 1.0x-geometry stores.
//   Grid 1536 = 3 mods x 512 m-tiles (XCD swizzle 8x192).
// ============================================================
#define LOADA(aa, kk)                                                        \
  {                                                                          \
    _Pragma("unroll") for (int mt = 0; mt < 2; ++mt)                         \
        aa[mt] = Afr[((kk) * 2 + mt) * 64 +                                  \
                     ((ln ^ (((kk) * 4 + quad) & 15)) + (quad << 4))];       \
  }

#define LOADB(bb, kk)                                                        \
  {                                                                          \
    _Pragma("unroll") for (int n2 = 0; n2 < 4; ++n2)                         \
        bb[n2] = bbase[((kk) * 4 + n2) * 64];                                \
  }

#define COMP(aa, bb)                                                     \
  {                                                                      \
    _Pragma("unroll") for (int mt = 0; mt < 2; ++mt)                     \
    {                                                                    \
      short8 af = __builtin_bit_cast(short8, aa[mt]);                    \
      _Pragma("unroll") for (int n2 = 0; n2 < 4; ++n2)                   \
          acc[mt][n2] = __builtin_amdgcn_mfma_f32_16x16x32_bf16(         \
              af, __builtin_bit_cast(short8, bb[n2]), acc[mt][n2], 0, 0, \
              0);                                                        \
    }                                                                    \
  }

__global__ __launch_bounds__(512, 4) void caps_fused(
    const float* __restrict__ x0, const float* __restrict__ x1, const float* __restrict__ x2,
    const uintx4* __restrict__ Bprep, const float* __restrict__ biasPrep,
    float* __restrict__ out) {
  __shared__ unsigned long long As64[48 * 128];  // 48 frags x 64 slots x 16 B

  const int tid = threadIdx.x;
  // XCD-chunk swizzle: 1536 = 8 XCDs x 192 contiguous blocks (bijective).
  const int bx0 = blockIdx.x;
  const int bx = (bx0 & 7) * 192 + (bx0 >> 3);
  const int mod = bx >> 9;           // 1536 = 3 x 512
  const int bm = bx & 511;           // m-tile (32 rows)
  const float* __restrict__ X = (mod == 0) ? x0 : ((mod == 1) ? x1 : x2);

  // ---- one-shot staging: 32 rows x 768 cols fp32, coalesced, 512 thr.
  // NONTEMPORAL: X is used exactly once per block; keeping it out of L2
  // preserves the XCD's Bprep slice (the round-15 single variable). ----
  const float* src = X + (size_t)bm * 32 * 768;
#pragma unroll
  for (int i = 0; i < 12; ++i) {
    const int idx = i * 2048 + tid * 4;          // flat float index in tile
    floatx4 f = __builtin_nontemporal_load((const floatx4*)(src + idx));
    const int m = (unsigned)idx / 768u;
    const int k = idx - m * 768;
    const int ks = k >> 5;
    const int kk = k & 31;
    const int qk = kk >> 3;                      // quad of k
    const int jh = (kk >> 2) & 1;                // which 8-byte half
    const int mt = m >> 4;
    const int lnn = m & 15;
    const int p = (ks * 4 + qk) & 15;            // slot-XOR spread
    const int slot = (lnn ^ p) + (qk << 4);
    unsigned long long w =
        ((unsigned long long)pk_bf16(f.z, f.w) << 32) | pk_bf16(f.x, f.y);
    As64[(((ks * 2 + mt) * 64 + slot) << 1) + jh] = w;
  }
  __syncthreads();  // the ONLY barrier

  const int lane = tid & 63;
  const int ln = lane & 15;
  const int quad = lane >> 4;
  const int wv = tid >> 6;  // wave id 0..7 == h: n16-range wv*4 .. wv*4+3

  const uintx4* Afr = (const uintx4*)As64;
  const uintx4* bbase = Bprep + (size_t)(mod * 8 + wv) * (96 * 64) + lane;

  floatx4 acc[2][4] = {};
  uintx4 a0[2], a1[2], a2[2], b0[4], b1[4], b2[4];

  LOADA(a0, 0); LOADB(b0, 0);
  LOADA(a1, 1); LOADB(b1, 1);
  LOADA(a2, 2); LOADB(b2, 2);
#pragma unroll
  for (int it = 0; it < 7; ++it) {     // fully unrolled: s compile-time
    const int s = 3 * it;
    COMP(a0, b0);
    LOADA(a0, s + 3); LOADB(b0, s + 3);
    COMP(a1, b1);
    LOADA(a1, s + 4); LOADB(b1, s + 4);
    COMP(a2, b2);
    LOADA(a2, s + 5); LOADB(b2, s + 5);
  }
  COMP(a0, b0);   // steps 21..23 drain
  COMP(a1, b1);
  COMP(a2, b2);

  // ---- epilogue: bias + squash + imm-offset stores (1.0x geometry) ----
  const int col0 = mod * 512 + wv * 64 + ln;
  float bias[4];
#pragma unroll
  for (int n2 = 0; n2 < 4; ++n2) bias[n2] = biasPrep[col0 + n2 * 16];

#pragma unroll
  for (int mt = 0; mt < 2; ++mt) {
    float* opm = out + (size_t)(bm * 32 + mt * 16 + quad * 4) * 1536 + col0;
#pragma unroll
    for (int jj = 0; jj < 4; ++jj) {
      float* opj = opm + jj * 1536;    // one 64-bit add per 4 stores
#pragma unroll
      for (int n2 = 0; n2 < 4; ++n2) {
        float u = acc[mt][n2][jj] + bias[n2];
        float s = u * u;
        s += __shfl_xor(s, 1);
        s += __shfl_xor(s, 2);
        s += __shfl_xor(s, 4);
#if __has_builtin(__builtin_amdgcn_rsqf) && __has_builtin(__builtin_amdgcn_rcpf)
        float sc = s * __builtin_amdgcn_rsqf(s + 1e-7f) *
                   __builtin_amdgcn_rcpf(1.0f + s);
#else
        float sc = s / ((1.0f + s) * sqrtf(s + 1e-7f));
#endif
        opj[n2 * 16] = u * sc;         // imm offsets 0/64/128/192 dwords
      }
    }
  }
}

// ============================================================
extern "C" void kernel_launch(void* const* d_in, const int* in_sizes, int n_in,
                              void* d_out, int out_size, void* d_ws, size_t ws_size,
                              hipStream_t stream) {
  const float* ximg = (const float*)d_in[0];
  const float* xcapt = (const float*)d_in[1];
  const float* xdct = (const float*)d_in[2];
  const float* Wi = (const float*)d_in[3];
  const float* bi = (const float*)d_in[4];
  const float* Wc = (const float*)d_in[5];
  const float* bc = (const float*)d_in[6];
  const float* Wd = (const float*)d_in[7];
  const float* bd = (const float*)d_in[8];

  uintx4* Bprep = (uintx4*)d_ws;                           // 2.25 MiB
  float* biasPrep = (float*)((char*)d_ws + 2304 * 1024);   // 6 KiB

  hipLaunchKernelGGL(prep_w, dim3(576), dim3(256), 0, stream,
                     Wi, Wc, Wd, bi, bc, bd, Bprep, biasPrep);
  hipLaunchKernelGGL(caps_fused, dim3(1536), dim3(512), 0, stream,
                     ximg, xcapt, xdct, (const uintx4*)Bprep, biasPrep,
                     (float*)d_out);
}

// Round 16
// 81.546 us; speedup vs baseline: 1.1379x; 1.1379x over previous
//
#include <hip/hip_runtime.h>

// ---------- types ----------
typedef __attribute__((ext_vector_type(8))) short short8;     // 8 bf16 (4 VGPRs)
typedef __attribute__((ext_vector_type(4))) float floatx4;    // MFMA C/D
typedef __attribute__((ext_vector_type(4))) unsigned int uintx4;

// ---------- fp32 -> packed bf16x2 (RNE) ----------
#if __has_builtin(__builtin_amdgcn_cvt_pk_bf16_f32)
typedef __attribute__((ext_vector_type(2))) __bf16 bf16x2;
__device__ __forceinline__ unsigned int pk_bf16(float a, float b) {
  bf16x2 v = __builtin_amdgcn_cvt_pk_bf16_f32(a, b);
  return __builtin_bit_cast(unsigned int, v);
}
#else
__device__ __forceinline__ unsigned int bf16_1(float f) {
  unsigned int u = __builtin_bit_cast(unsigned int, f);
  return (u + 0x7fffu + ((u >> 16) & 1u)) >> 16;
}
__device__ __forceinline__ unsigned int pk_bf16(float a, float b) {
  return bf16_1(a) | (bf16_1(b) << 16);
}
#endif

// Fragment conventions (verified rounds 0-15, absmax 3.9e-3):
//   A-frag (16x16x32): lane(ln,quad) holds A[m=ln][k=quad*8+j], j=0..7
//   B-frag:            lane(ln,quad) holds B[n=ln][k=quad*8+j]  (B[k][n]=W[c][r][k], n=r*8+c)
//   C/D:               col=ln, row=quad*4+reg
// Bprep frag id: Fb = ((mod*8 + h)*24 + ks)*4 + nt, n16 = h*4+nt; frag = 64 lanes x 16B.
//
// LEDGER (do not revisit without new evidence):
// * STORE GEOMETRY LOAD-BEARING: scalar dword stores, 16 consecutive dwords
//   per 16-lane group x 4 rows/instr = 1.0x writes. Anything else 1.5-3.0x.
// * NT STORES: 3x write amplification (r3).
// * PERMUTED-B + direct stores: silent transpose (r6).
// * REG-SPILL SIGNATURE: WRITE/FETCH balloon + 2.4x dur (r7).
// * 64-ROW 16-WAVE BLOCKS: quantization tax (r9).
// * OCCUPANCY 43->76%: zero effect (r10).  PREFETCH 2->3 deep: zero (r11).
// * 64x256 COL-SPLIT: X HBM doubles, L3 does not absorb (r12).
// * K-STAGGER: zero (r13).  VALU DIET: VALUBusy 29->19, zero (r14).
// * NT X-LOADS (r15): CONFIRMED B-eviction-by-X-streaming — profiled
//   -23 us (B stays L2-resident, MfmaUtil 13.7->17.3). But nt also
//   bypasses the memory-side L3 (MALL-noalloc) -> bench lost X's
//   cross-iteration L3 residency, net +8 us. NT couples both caches.
// ROUND-16: split the policies with SC1. Agent-scope (sc1) loads bypass
// the per-XCD L2 (no allocate — the cross-XCD coherence path) but ARE
// served/retained by the memory-side Infinity Cache. X staging via
// inline-asm global_load_dwordx4 sc1: B keeps L2, X keeps L3.

// ============================================================
// Prepass W: [8][64][768] fp32 -> bf16 B-fragments; bias permuted to n-order.
// ============================================================
__global__ __launch_bounds__(256) void prep_w(
    const float* __restrict__ Wi, const float* __restrict__ Wc, const float* __restrict__ Wd,
    const float* __restrict__ bi, const float* __restrict__ bc, const float* __restrict__ bd,
    uintx4* __restrict__ Bprep, float* __restrict__ biasPrep) {
  const int t = blockIdx.x * 256 + threadIdx.x;  // 0 .. 147455
  const int l = t & 63;
  const int frag = t >> 6;             // 0 .. 2303
  const int nt = frag & 3;
  const int q = frag >> 2;
  const int ks = q % 24;
  const int q2 = q / 24;
  const int h = q2 & 7;
  const int mod = q2 >> 3;
  const int n16 = h * 4 + nt;
  const float* __restrict__ W = (mod == 0) ? Wi : ((mod == 1) ? Wc : Wd);

  const int n = n16 * 16 + (l & 15);
  const int r = n >> 3;
  const int c = n & 7;
  const int i0 = ks * 32 + (l >> 4) * 8;
  const float* src = W + (size_t)(c * 64 + r) * 768 + i0;
  floatx4 f0 = *(const floatx4*)(src);
  floatx4 f1 = *(const floatx4*)(src + 4);
  uintx4 p;
  p.x = pk_bf16(f0.x, f0.y);
  p.y = pk_bf16(f0.z, f0.w);
  p.z = pk_bf16(f1.x, f1.y);
  p.w = pk_bf16(f1.z, f1.w);
  Bprep[(size_t)frag * 64 + l] = p;

  if (t < 1536) {
    const int m2 = t >> 9;
    const int nn = t & 511;
    const float* bb = (m2 == 0) ? bi : ((m2 == 1) ? bc : bd);
    biasPrep[t] = bb[(nn & 7) * 64 + (nn >> 3)];
  }
}

// ============================================================
// Fused GEMM + squash. ROUND-16 = round-14 kernel with ONE change:
// the 12 staging X loads are SC1 (L2-bypass, L3-retained) inline asm.
// Issue all 12 -> one s_waitcnt vmcnt(0) -> sched_barrier(0) (rule 18)
// -> pack to LDS. Everything else byte-identical to r14.
//   Block: 512 thr / 8 waves; wave owns 32x64 (acc[2][4] = 32 AGPR).
//   A (32x768) staged once as bf16 frags in 48 KB LDS (slot-XOR), one
//   barrier, fully-unrolled 24-step K-loop, 3-deep register prefetch.
//   Epilogue: shuffle-squash + rsq/rcp + imm-offset 1.0x-geometry stores.
//   Grid 1536 = 3 mods x 512 m-tiles (XCD swizzle 8x192).
// ============================================================
#define LOADA(aa, kk)                                                        \
  {                                                                          \
    _Pragma("unroll") for (int mt = 0; mt < 2; ++mt)                         \
        aa[mt] = Afr[((kk) * 2 + mt) * 64 +                                  \
                     ((ln ^ (((kk) * 4 + quad) & 15)) + (quad << 4))];       \
  }

#define LOADB(bb, kk)                                                        \
  {                                                                          \
    _Pragma("unroll") for (int n2 = 0; n2 < 4; ++n2)                         \
        bb[n2] = bbase[((kk) * 4 + n2) * 64];                                \
  }

#define COMP(aa, bb)                                                     \
  {                                                                      \
    _Pragma("unroll") for (int mt = 0; mt < 2; ++mt)                     \
    {                                                                    \
      short8 af = __builtin_bit_cast(short8, aa[mt]);                    \
      _Pragma("unroll") for (int n2 = 0; n2 < 4; ++n2)                   \
          acc[mt][n2] = __builtin_amdgcn_mfma_f32_16x16x32_bf16(         \
              af, __builtin_bit_cast(short8, bb[n2]), acc[mt][n2], 0, 0, \
              0);                                                        \
    }                                                                    \
  }

__global__ __launch_bounds__(512, 4) void caps_fused(
    const float* __restrict__ x0, const float* __restrict__ x1, const float* __restrict__ x2,
    const uintx4* __restrict__ Bprep, const float* __restrict__ biasPrep,
    float* __restrict__ out) {
  __shared__ unsigned long long As64[48 * 128];  // 48 frags x 64 slots x 16 B

  const int tid = threadIdx.x;
  // XCD-chunk swizzle: 1536 = 8 XCDs x 192 contiguous blocks (bijective).
  const int bx0 = blockIdx.x;
  const int bx = (bx0 & 7) * 192 + (bx0 >> 3);
  const int mod = bx >> 9;           // 1536 = 3 x 512
  const int bm = bx & 511;           // m-tile (32 rows)
  const float* __restrict__ X = (mod == 0) ? x0 : ((mod == 1) ? x1 : x2);

  // ---- one-shot staging: 32 rows x 768 cols fp32, coalesced, 512 thr.
  // SC1 loads: bypass per-XCD L2 (keep Bprep resident) while remaining
  // L3-cached (keep cross-iteration X residency). Issue all 12, wait once.
  const float* src = X + (size_t)bm * 32 * 768;
  const float* base = src + tid * 4;
  floatx4 fr[12];
#pragma unroll
  for (int i = 0; i < 12; ++i) {
    const float* p = base + i * 2048;
    asm volatile("global_load_dwordx4 %0, %1, off sc1"
                 : "=&v"(fr[i]) : "v"(p));
  }
  asm volatile("s_waitcnt vmcnt(0)" ::: "memory");
  __builtin_amdgcn_sched_barrier(0);   // rule 18: pin consumers after wait
#pragma unroll
  for (int i = 0; i < 12; ++i) {
    const int idx = i * 2048 + tid * 4;          // flat float index in tile
    floatx4 f = fr[i];
    const int m = (unsigned)idx / 768u;
    const int k = idx - m * 768;
    const int ks = k >> 5;
    const int kk = k & 31;
    const int qk = kk >> 3;                      // quad of k
    const int jh = (kk >> 2) & 1;                // which 8-byte half
    const int mt = m >> 4;
    const int lnn = m & 15;
    const int p = (ks * 4 + qk) & 15;            // slot-XOR spread
    const int slot = (lnn ^ p) + (qk << 4);
    unsigned long long w =
        ((unsigned long long)pk_bf16(f.z, f.w) << 32) | pk_bf16(f.x, f.y);
    As64[(((ks * 2 + mt) * 64 + slot) << 1) + jh] = w;
  }
  __syncthreads();  // the ONLY barrier

  const int lane = tid & 63;
  const int ln = lane & 15;
  const int quad = lane >> 4;
  const int wv = tid >> 6;  // wave id 0..7 == h: n16-range wv*4 .. wv*4+3

  const uintx4* Afr = (const uintx4*)As64;
  const uintx4* bbase = Bprep + (size_t)(mod * 8 + wv) * (96 * 64) + lane;

  floatx4 acc[2][4] = {};
  uintx4 a0[2], a1[2], a2[2], b0[4], b1[4], b2[4];

  LOADA(a0, 0); LOADB(b0, 0);
  LOADA(a1, 1); LOADB(b1, 1);
  LOADA(a2, 2); LOADB(b2, 2);
#pragma unroll
  for (int it = 0; it < 7; ++it) {     // fully unrolled: s compile-time
    const int s = 3 * it;
    COMP(a0, b0);
    LOADA(a0, s + 3); LOADB(b0, s + 3);
    COMP(a1, b1);
    LOADA(a1, s + 4); LOADB(b1, s + 4);
    COMP(a2, b2);
    LOADA(a2, s + 5); LOADB(b2, s + 5);
  }
  COMP(a0, b0);   // steps 21..23 drain
  COMP(a1, b1);
  COMP(a2, b2);

  // ---- epilogue: bias + squash + imm-offset stores (1.0x geometry) ----
  const int col0 = mod * 512 + wv * 64 + ln;
  float bias[4];
#pragma unroll
  for (int n2 = 0; n2 < 4; ++n2) bias[n2] = biasPrep[col0 + n2 * 16];

#pragma unroll
  for (int mt = 0; mt < 2; ++mt) {
    float* opm = out + (size_t)(bm * 32 + mt * 16 + quad * 4) * 1536 + col0;
#pragma unroll
    for (int jj = 0; jj < 4; ++jj) {
      float* opj = opm + jj * 1536;    // one 64-bit add per 4 stores
#pragma unroll
      for (int n2 = 0; n2 < 4; ++n2) {
        float u = acc[mt][n2][jj] + bias[n2];
        float s = u * u;
        s += __shfl_xor(s, 1);
        s += __shfl_xor(s, 2);
        s += __shfl_xor(s, 4);
#if __has_builtin(__builtin_amdgcn_rsqf) && __has_builtin(__builtin_amdgcn_rcpf)
        float sc = s * __builtin_amdgcn_rsqf(s + 1e-7f) *
                   __builtin_amdgcn_rcpf(1.0f + s);
#else
        float sc = s / ((1.0f + s) * sqrtf(s + 1e-7f));
#endif
        opj[n2 * 16] = u * sc;         // imm offsets 0/64/128/192 dwords
      }
    }
  }
}

// ============================================================
extern "C" void kernel_launch(void* const* d_in, const int* in_sizes, int n_in,
                              void* d_out, int out_size, void* d_ws, size_t ws_size,
                              hipStream_t stream) {
  const float* ximg = (const float*)d_in[0];
  const float* xcapt = (const float*)d_in[1];
  const float* xdct = (const float*)d_in[2];
  const float* Wi = (const float*)d_in[3];
  const float* bi = (const float*)d_in[4];
  const float* Wc = (const float*)d_in[5];
  const float* bc = (const float*)d_in[6];
  const float* Wd = (const float*)d_in[7];
  const float* bd = (const float*)d_in[8];

  uintx4* Bprep = (uintx4*)d_ws;                           // 2.25 MiB
  float* biasPrep = (float*)((char*)d_ws + 2304 * 1024);   // 6 KiB

  hipLaunchKernelGGL(prep_w, dim3(576), dim3(256), 0, stream,
                     Wi, Wc, Wd, bi, bc, bd, Bprep, biasPrep);
  hipLaunchKernelGGL(caps_fused, dim3(1536), dim3(512), 0, stream,
                     ximg, xcapt, xdct, (const uintx4*)Bprep, biasPrep,
                     (float*)d_out);
}